// Round 2
// baseline (41719.827 us; speedup 1.0000x reference)
//
#include <hip/hip_runtime.h>

#define T_STEPS 512
#define BH      65536                 // B*H = 64*1024
#define STACK   (T_STEPS * BH)        // 33554432
#define NBLK    256
#define NTHR    256

__device__ __forceinline__ float sigf(float x)  { return 1.0f / (1.0f + __expf(-x)); }
__device__ __forceinline__ float tanhf_(float x){ return 2.0f / (1.0f + __expf(-2.0f * x)) - 1.0f; }

__device__ __forceinline__ void dot4(float& a, const float4& w, const float4& c) {
  a = fmaf(w.x, c.x, a);
  a = fmaf(w.y, c.y, a);
  a = fmaf(w.z, c.z, a);
  a = fmaf(w.w, c.w, a);
}

// Monotonic 2-level grid barrier. phase k: each block has added k+1 times.
// Level-1: 8 counters (ws[g*64]), 32 blocks each; level-2 root (ws[512]).
// Release/acquire at agent scope gives the buffer_wbl2 / buffer_inv needed
// for cross-XCD h visibility (per-XCD L2s are not coherent).
__device__ __forceinline__ void grid_barrier(int* ws, int phase, int blk, int tid) {
  __syncthreads();   // compiler emits vmcnt(0) drain: all this block's h stores complete
  if (tid == 0) {
    const int g = blk & 7;
    __hip_atomic_fetch_add(&ws[g * 64], 1, __ATOMIC_RELEASE, __HIP_MEMORY_SCOPE_AGENT);
    if (blk < 8) {  // leader of group blk
      while (__hip_atomic_load(&ws[blk * 64], __ATOMIC_RELAXED, __HIP_MEMORY_SCOPE_AGENT) < 32 * (phase + 1))
        __builtin_amdgcn_s_sleep(1);
      (void)__hip_atomic_load(&ws[blk * 64], __ATOMIC_ACQUIRE, __HIP_MEMORY_SCOPE_AGENT);
      __hip_atomic_fetch_add(&ws[512], 1, __ATOMIC_RELEASE, __HIP_MEMORY_SCOPE_AGENT);
    }
    while (__hip_atomic_load(&ws[512], __ATOMIC_RELAXED, __HIP_MEMORY_SCOPE_AGENT) < 8 * (phase + 1))
      __builtin_amdgcn_s_sleep(1);
    (void)__hip_atomic_load(&ws[512], __ATOMIC_ACQUIRE, __HIP_MEMORY_SCOPE_AGENT);  // one inv
  }
  __syncthreads();
}

__global__ __launch_bounds__(NTHR, 1)
void lstm_k(const float* __restrict__ X, const float* __restrict__ hx0,
            const float* __restrict__ cx0, const float* __restrict__ W,
            const float* __restrict__ bias, float* __restrict__ out,
            int* __restrict__ ws)
{
  __shared__ float part[4160];  // 4 k-seg x 16 rows x 65 (padded) partials

  const int tid  = threadIdx.x;
  const int blk  = blockIdx.x;
  const int sw   = tid >> 6;        // k-segment (wave id, 0..3)
  const int lane = tid & 63;
  const int bq   = lane >> 2;       // batch quad (0..15)
  const int gq   = lane & 3;        // gate index (0..3) -> rows gq*1024 + blk*4 + u
  const int bb   = tid >> 2;        // epilogue: batch (0..63)
  const int jj   = tid & 3;         // epilogue: unit within block (0..3)
  const int col  = blk * 4 + jj;    // global hidden unit

  // One-time cleanse: write back + invalidate stale 0xAA-poison L2 lines
  // (from the harness memset) before any h store can be clobbered by a
  // late dirty eviction. Then grid-sync so every L2 is clean first.
  if (tid == 0) __threadfence_system();
  grid_barrier(ws, 0, blk, tid);

  const float bv0 = bias[col], bv1 = bias[1024 + col],
              bv2 = bias[2048 + col], bv3 = bias[3072 + col];
  float creg = cx0[(size_t)bb * 1024 + col];

  // W row pointers (k-contiguous), offset to this thread's x k-segment.
  const float4* wp[4];
#pragma unroll
  for (int u = 0; u < 4; ++u)
    wp[u] = reinterpret_cast<const float4*>(
        W + (size_t)(gq * 1024 + blk * 4 + u) * 2048 + sw * 256);

  // x pointers for t=0 (advance by t*BH/4 per step).
  const float4* xb[4];
#pragma unroll
  for (int bi = 0; bi < 4; ++bi)
    xb[bi] = reinterpret_cast<const float4*>(
        X + (size_t)(bq * 4 + bi) * 1024 + sw * 256);

  float acc[4][4];

  for (int t = 0; t < T_STEPS; ++t) {
#pragma unroll
    for (int u = 0; u < 4; ++u)
#pragma unroll
      for (int bi = 0; bi < 4; ++bi) acc[u][bi] = 0.0f;

    // ---- x half: k in [sw*256, sw*256+256) of the input part ----
    const float4* xt0 = xb[0] + (size_t)t * (BH / 4);
    const float4* xt1 = xb[1] + (size_t)t * (BH / 4);
    const float4* xt2 = xb[2] + (size_t)t * (BH / 4);
    const float4* xt3 = xb[3] + (size_t)t * (BH / 4);
#pragma unroll 4
    for (int g = 0; g < 64; ++g) {
      float4 w0 = wp[0][g], w1 = wp[1][g], w2 = wp[2][g], w3 = wp[3][g];
      float4 c0 = xt0[g], c1 = xt1[g], c2 = xt2[g], c3 = xt3[g];
      dot4(acc[0][0], w0, c0); dot4(acc[0][1], w0, c1); dot4(acc[0][2], w0, c2); dot4(acc[0][3], w0, c3);
      dot4(acc[1][0], w1, c0); dot4(acc[1][1], w1, c1); dot4(acc[1][2], w1, c2); dot4(acc[1][3], w1, c3);
      dot4(acc[2][0], w2, c0); dot4(acc[2][1], w2, c1); dot4(acc[2][2], w2, c2); dot4(acc[2][3], w2, c3);
      dot4(acc[3][0], w3, c0); dot4(acc[3][1], w3, c1); dot4(acc[3][2], w3, c2); dot4(acc[3][3], w3, c3);
    }

    // ---- h half: k in [1024 + sw*256, ...) ----
    const float* hsrc = (t == 0) ? hx0 : out + (size_t)(t - 1) * BH;
    const float4* h0 = reinterpret_cast<const float4*>(hsrc + (size_t)(bq * 4 + 0) * 1024 + sw * 256);
    const float4* h1 = reinterpret_cast<const float4*>(hsrc + (size_t)(bq * 4 + 1) * 1024 + sw * 256);
    const float4* h2 = reinterpret_cast<const float4*>(hsrc + (size_t)(bq * 4 + 2) * 1024 + sw * 256);
    const float4* h3 = reinterpret_cast<const float4*>(hsrc + (size_t)(bq * 4 + 3) * 1024 + sw * 256);
    const float4* q0 = wp[0] + 256;  // +1024 floats: W's h columns
    const float4* q1 = wp[1] + 256;
    const float4* q2 = wp[2] + 256;
    const float4* q3 = wp[3] + 256;
#pragma unroll 4
    for (int g = 0; g < 64; ++g) {
      float4 w0 = q0[g], w1 = q1[g], w2 = q2[g], w3 = q3[g];
      float4 c0 = h0[g], c1 = h1[g], c2 = h2[g], c3 = h3[g];
      dot4(acc[0][0], w0, c0); dot4(acc[0][1], w0, c1); dot4(acc[0][2], w0, c2); dot4(acc[0][3], w0, c3);
      dot4(acc[1][0], w1, c0); dot4(acc[1][1], w1, c1); dot4(acc[1][2], w1, c2); dot4(acc[1][3], w1, c3);
      dot4(acc[2][0], w2, c0); dot4(acc[2][1], w2, c1); dot4(acc[2][2], w2, c2); dot4(acc[2][3], w2, c3);
      dot4(acc[3][0], w3, c0); dot4(acc[3][1], w3, c1); dot4(acc[3][2], w3, c2); dot4(acc[3][3], w3, c3);
    }

    // ---- partial reduce over the 4 k-segments via LDS ----
#pragma unroll
    for (int u = 0; u < 4; ++u)
#pragma unroll
      for (int bi = 0; bi < 4; ++bi)
        part[sw * 1040 + (gq * 4 + u) * 65 + bq * 4 + bi] = acc[u][bi];
    __syncthreads();

    float v0 = bv0, v1 = bv1, v2 = bv2, v3 = bv3;
#pragma unroll
    for (int ss = 0; ss < 4; ++ss) {
      v0 += part[ss * 1040 + jj * 65 + bb];
      v1 += part[ss * 1040 + (4 + jj) * 65 + bb];
      v2 += part[ss * 1040 + (8 + jj) * 65 + bb];
      v3 += part[ss * 1040 + (12 + jj) * 65 + bb];
    }
    const float fg = sigf(v0), ig = sigf(v1), gg = tanhf_(v2), og = sigf(v3);
    creg = fg * creg + ig * gg;
    const float hh = og * tanhf_(creg);

    // agent-scope store: h must reach the coherence point for other XCDs
    __hip_atomic_store(out + (size_t)t * BH + (size_t)bb * 1024 + col, hh,
                       __ATOMIC_RELAXED, __HIP_MEMORY_SCOPE_AGENT);

    if (t == T_STEPS - 1) {
      out[(size_t)STACK + (size_t)bb * 1024 + col] = hh;         // hx
      out[(size_t)STACK + BH + (size_t)bb * 1024 + col] = creg;  // cx
    } else {
      grid_barrier(ws, t + 1, blk, tid);  // also protects LDS `part` reuse
    }
  }
}

extern "C" void kernel_launch(void* const* d_in, const int* in_sizes, int n_in,
                              void* d_out, int out_size, void* d_ws, size_t ws_size,
                              hipStream_t stream) {
  (void)in_sizes; (void)n_in; (void)out_size; (void)ws_size;
  const float* X    = (const float*)d_in[0];
  const float* hx0  = (const float*)d_in[1];
  const float* cx0  = (const float*)d_in[2];
  const float* W    = (const float*)d_in[3];
  const float* bias = (const float*)d_in[4];
  float* out = (float*)d_out;
  int* ws = (int*)d_ws;

  // zero the barrier counters (d_ws is re-poisoned to 0xAA before every launch)
  hipMemsetAsync(d_ws, 0, 4096, stream);
  lstm_k<<<dim3(NBLK), dim3(NTHR), 0, stream>>>(X, hx0, cx0, W, bias, out, ws);
}

// Round 3
// 39785.687 us; speedup vs baseline: 1.0486x; 1.0486x over previous
//
#include <hip/hip_runtime.h>

#define T_STEPS 512
#define BH      65536                 // B*H = 64*1024
#define STACK   (T_STEPS * BH)        // 33554432
#define NBLK    256
#define NTHR    512

__device__ __forceinline__ float sigf(float x)  { return 1.0f / (1.0f + __expf(-x)); }
__device__ __forceinline__ float tanhf_(float x){ return 2.0f / (1.0f + __expf(-2.0f * x)) - 1.0f; }

__device__ __forceinline__ void dot4(float& a, const float4& w, const float4& c) {
  a = fmaf(w.x, c.x, a);
  a = fmaf(w.y, c.y, a);
  a = fmaf(w.z, c.z, a);
  a = fmaf(w.w, c.w, a);
}

// Store straight to the LLC (bypass L1+L2). Consumers on other XCDs read these
// t-indexed addresses with PLAIN cached loads: first touch is post-barrier, so
// their L2 miss fetches the fresh LLC copy. No buffer_inv needed anywhere.
__device__ __forceinline__ void store_llc(float* p, float v) {
  asm volatile("global_store_dword %0, %1, off sc0 sc1" :: "v"(p), "v"(v) : "memory");
}

// ---- relaxed monotonic 2-level grid barrier (NO acquire -> L2 stays valid) ----
__device__ __forceinline__ void barrier_arrive(int* ws, int blk, int tid) {
  // every wave drains its own vmem (h stores have reached the LLC once vmcnt==0)
  asm volatile("s_waitcnt vmcnt(0)" ::: "memory");
  __syncthreads();
  if (tid == 0)
    __hip_atomic_fetch_add(&ws[(blk & 7) * 64], 1, __ATOMIC_RELAXED, __HIP_MEMORY_SCOPE_AGENT);
}

__device__ __forceinline__ void barrier_wait(int* ws, int n, int blk, int tid) {
  if (tid == 0) {
    if (blk < 8) {  // leader of group blk
      while (__hip_atomic_load(&ws[blk * 64], __ATOMIC_RELAXED, __HIP_MEMORY_SCOPE_AGENT) < 32 * n)
        __builtin_amdgcn_s_sleep(1);
      __hip_atomic_fetch_add(&ws[512], 1, __ATOMIC_RELAXED, __HIP_MEMORY_SCOPE_AGENT);
    }
    while (__hip_atomic_load(&ws[512], __ATOMIC_RELAXED, __HIP_MEMORY_SCOPE_AGENT) < 8 * n)
      __builtin_amdgcn_s_sleep(1);
  }
  __syncthreads();
  asm volatile("" ::: "memory");  // compiler fence: keep h loads below the wait
}

__global__ __launch_bounds__(NTHR, 2)
void lstm_k(const float* __restrict__ X, const float* __restrict__ hx0,
            const float* __restrict__ cx0, const float* __restrict__ W,
            const float* __restrict__ bias, float* __restrict__ out,
            int* __restrict__ ws)
{
  __shared__ float part[8 * 1040];  // 8 k-seg x 16 rows x 65 (padded)

  const int tid  = threadIdx.x;
  const int blk  = blockIdx.x;
  const int sw   = tid >> 6;        // k-segment (wave id, 0..7), 128 floats each
  const int lane = tid & 63;
  const int bq   = lane >> 2;       // batch quad (0..15)
  const int gq   = lane & 3;        // gate index (0..3)
  const int bb   = tid >> 2;        // epilogue (tid<256): batch
  const int jj   = tid & 3;         // epilogue: unit within block
  const int col  = blk * 4 + jj;    // global hidden unit

  // W row pointers, k-contiguous. Row = gate*1024 + blk*4 + u.
  const float4* wx[4];  // x half: k in [sw*128, +128)
  const float4* wh[4];  // h half: k in [1024 + sw*128, +128)
#pragma unroll
  for (int u = 0; u < 4; ++u) {
    wx[u] = reinterpret_cast<const float4*>(
        W + (size_t)(gq * 1024 + blk * 4 + u) * 2048 + sw * 128);
    wh[u] = wx[u] + 256;  // +1024 floats
  }
  const float4* xb[4];
#pragma unroll
  for (int bi = 0; bi < 4; ++bi)
    xb[bi] = reinterpret_cast<const float4*>(
        X + (size_t)(bq * 4 + bi) * 1024 + sw * 128);

  float bv0 = 0.f, bv1 = 0.f, bv2 = 0.f, bv3 = 0.f, creg = 0.f;
  if (tid < 256) {
    bv0 = bias[col]; bv1 = bias[1024 + col]; bv2 = bias[2048 + col]; bv3 = bias[3072 + col];
    creg = cx0[(size_t)bb * 1024 + col];
  }

  // phase 1: everyone launched (also exercises the barrier once before use)
  barrier_arrive(ws, blk, tid);
  barrier_wait(ws, 1, blk, tid);

  float acc[4][4];

#pragma unroll 1
  for (int t = 0; t < T_STEPS; ++t) {
#pragma unroll
    for (int u = 0; u < 4; ++u)
#pragma unroll
      for (int bi = 0; bi < 4; ++bi) acc[u][bi] = 0.0f;

    // ---- x half (no h dependency; overlaps other blocks finishing t-1) ----
    const float4* xt0 = xb[0] + (size_t)t * (BH / 4);
    const float4* xt1 = xb[1] + (size_t)t * (BH / 4);
    const float4* xt2 = xb[2] + (size_t)t * (BH / 4);
    const float4* xt3 = xb[3] + (size_t)t * (BH / 4);
#pragma unroll 4
    for (int g = 0; g < 32; ++g) {
      float4 w0 = wx[0][g], w1 = wx[1][g], w2 = wx[2][g], w3 = wx[3][g];
      float4 c0 = xt0[g], c1 = xt1[g], c2 = xt2[g], c3 = xt3[g];
      dot4(acc[0][0], w0, c0); dot4(acc[0][1], w0, c1); dot4(acc[0][2], w0, c2); dot4(acc[0][3], w0, c3);
      dot4(acc[1][0], w1, c0); dot4(acc[1][1], w1, c1); dot4(acc[1][2], w1, c2); dot4(acc[1][3], w1, c3);
      dot4(acc[2][0], w2, c0); dot4(acc[2][1], w2, c1); dot4(acc[2][2], w2, c2); dot4(acc[2][3], w2, c3);
      dot4(acc[3][0], w3, c0); dot4(acc[3][1], w3, c1); dot4(acc[3][2], w3, c2); dot4(acc[3][3], w3, c3);
    }

    // ---- h(t-1) must be globally visible from here on ----
    if (t > 0) barrier_wait(ws, t + 1, blk, tid);

    const float* hsrc = (t == 0) ? hx0 : out + (size_t)(t - 1) * BH;
    const float4* h0 = reinterpret_cast<const float4*>(hsrc + (size_t)(bq * 4 + 0) * 1024 + sw * 128);
    const float4* h1 = reinterpret_cast<const float4*>(hsrc + (size_t)(bq * 4 + 1) * 1024 + sw * 128);
    const float4* h2 = reinterpret_cast<const float4*>(hsrc + (size_t)(bq * 4 + 2) * 1024 + sw * 128);
    const float4* h3 = reinterpret_cast<const float4*>(hsrc + (size_t)(bq * 4 + 3) * 1024 + sw * 128);
#pragma unroll 4
    for (int g = 0; g < 32; ++g) {
      float4 w0 = wh[0][g], w1 = wh[1][g], w2 = wh[2][g], w3 = wh[3][g];
      float4 c0 = h0[g], c1 = h1[g], c2 = h2[g], c3 = h3[g];
      dot4(acc[0][0], w0, c0); dot4(acc[0][1], w0, c1); dot4(acc[0][2], w0, c2); dot4(acc[0][3], w0, c3);
      dot4(acc[1][0], w1, c0); dot4(acc[1][1], w1, c1); dot4(acc[1][2], w1, c2); dot4(acc[1][3], w1, c3);
      dot4(acc[2][0], w2, c0); dot4(acc[2][1], w2, c1); dot4(acc[2][2], w2, c2); dot4(acc[2][3], w2, c3);
      dot4(acc[3][0], w3, c0); dot4(acc[3][1], w3, c1); dot4(acc[3][2], w3, c2); dot4(acc[3][3], w3, c3);
    }

    // ---- reduce 8 k-segments via LDS ----
#pragma unroll
    for (int u = 0; u < 4; ++u)
#pragma unroll
      for (int bi = 0; bi < 4; ++bi)
        part[sw * 1040 + (gq * 4 + u) * 65 + bq * 4 + bi] = acc[u][bi];
    __syncthreads();

    if (tid < 256) {
      float v0 = bv0, v1 = bv1, v2 = bv2, v3 = bv3;
#pragma unroll
      for (int ss = 0; ss < 8; ++ss) {
        v0 += part[ss * 1040 + jj * 65 + bb];
        v1 += part[ss * 1040 + (4 + jj) * 65 + bb];
        v2 += part[ss * 1040 + (8 + jj) * 65 + bb];
        v3 += part[ss * 1040 + (12 + jj) * 65 + bb];
      }
      const float fg = sigf(v0), ig = sigf(v1), gg = tanhf_(v2), og = sigf(v3);
      creg = fg * creg + ig * gg;
      const float hh = og * tanhf_(creg);

      store_llc(out + (size_t)t * BH + (size_t)bb * 1024 + col, hh);

      if (t == T_STEPS - 1) {
        out[(size_t)STACK + (size_t)bb * 1024 + col] = hh;         // hx
        out[(size_t)STACK + BH + (size_t)bb * 1024 + col] = creg;  // cx
      }
    }

    if (t < T_STEPS - 1) barrier_arrive(ws, blk, tid);
  }
}

extern "C" void kernel_launch(void* const* d_in, const int* in_sizes, int n_in,
                              void* d_out, int out_size, void* d_ws, size_t ws_size,
                              hipStream_t stream) {
  (void)in_sizes; (void)n_in; (void)out_size; (void)ws_size;
  const float* X    = (const float*)d_in[0];
  const float* hx0  = (const float*)d_in[1];
  const float* cx0  = (const float*)d_in[2];
  const float* W    = (const float*)d_in[3];
  const float* bias = (const float*)d_in[4];
  float* out = (float*)d_out;
  int* ws = (int*)d_ws;

  // zero the barrier counters (d_ws is re-poisoned to 0xAA before every launch)
  hipMemsetAsync(d_ws, 0, 4096, stream);
  lstm_k<<<dim3(NBLK), dim3(NTHR), 0, stream>>>(X, hx0, cx0, W, bias, out, ws);
}